// Round 4
// baseline (2885.248 us; speedup 1.0000x reference)
//
#include <hip/hip_runtime.h>
#include <hip/hip_fp16.h>

// R9 = R8 resubmission (bench infra failed; no counters). One change:
// removed the __threadfence() between prepass and scan — the gx ws round
// trip is same-thread RAW (producer lane == consumer lane), and a device
// fence's buffer_wbl2 would evict the L2-resident gx slice toward HBM.
//
// Design (R8): all-register Wh scan + chunked block-local gx prepass.
// R7 was LDS-pipe-bound (whn re-read 128KB/CU-step; ~2500 LDS cyc vs 580
// MFMA cyc). Fix: all 6 Wh tiles register/AGPR-resident (192 regs). The
// freed budget evicts the x-GEMM: per 32-step chunk, prepass computes
// gx=(x@Wx+b) (fp16, log2e-prescaled; R6-validated) into a private 768KB
// ws slice (L2-resident, 3MB/XCD), consumed as 3 coalesced dwordx4/lane.
// Phases per chunk: [A] x->LDS A-frags  [B] prepass (wxr live)
// [C] scan 32 steps (whN live). ws need 25.17MB; else gru_fb fallback.

typedef short v8s __attribute__((ext_vector_type(8)));   // 8 bf16
typedef float f32x4 __attribute__((ext_vector_type(4)));
typedef unsigned int u32x4 __attribute__((ext_vector_type(4)));
typedef unsigned int u32x2 __attribute__((ext_vector_type(2)));

#define LOG2E 1.4426950408889634f
#define CHUNK 32
#define NCHUNK 32
#define WS_NEED (32ull * CHUNK * 24576ull)   // 25,165,824 B

__device__ __forceinline__ unsigned short f2b(float f) {
    unsigned int u = __float_as_uint(f);
    u += 0x7FFFu + ((u >> 16) & 1u);       // RNE
    return (unsigned short)(u >> 16);
}
__device__ __forceinline__ float b2f(unsigned short h) {
    return __uint_as_float(((unsigned int)h) << 16);
}
__device__ __forceinline__ unsigned short f2h(float f) {
    return __half_as_ushort(__float2half_rn(f));
}
__device__ __forceinline__ float hxu(unsigned int u, int hi) {
    unsigned short b = (unsigned short)(hi ? (u >> 16) : (u & 0xFFFFu));
    return __half2float(__ushort_as_half(b));
}
__device__ __forceinline__ v8s cvt8(f32x4 a, f32x4 b) {
    v8s r;
#pragma unroll
    for (int j = 0; j < 4; ++j) { r[j] = (short)f2b(a[j]); r[4 + j] = (short)f2b(b[j]); }
    return r;
}
__device__ __forceinline__ v8s wfrag(const float* src, float s) {
    f32x4 a = *(const f32x4*)src, b = *(const f32x4*)(src + 4);
    a *= s; b *= s;
    return cvt8(a, b);
}
__device__ __forceinline__ float rcpf(float v) {
#if __has_builtin(__builtin_amdgcn_rcpf)
    return __builtin_amdgcn_rcpf(v);
#else
    return 1.0f / v;
#endif
}
__device__ __forceinline__ float exp2f_(float v) {
#if __has_builtin(__builtin_amdgcn_exp2f)
    return __builtin_amdgcn_exp2f(v);
#else
    return __exp2f(v);
#endif
}
// sigmoid of log2e-prescaled preactivation (HW-validated R6)
__device__ __forceinline__ float sg(float v) { return rcpf(1.0f + exp2f_(-v)); }
// unscaled (fallback kernel)
__device__ __forceinline__ float sigm(float v) {
    float e = __expf(-fmaxf(v, -30.0f));
    return rcpf(1.0f + e);
}
__device__ __forceinline__ float tanh_(float v) {
    float vc = fmaxf(fminf(v, 30.0f), -30.0f);
    float e = __expf(-2.0f * vc);
    return (1.0f - e) * rcpf(1.0f + e);
}
__device__ __forceinline__ f32x4 MF(v8s a, v8s b, f32x4 c) {
    return __builtin_amdgcn_mfma_f32_16x16x32_bf16(a, b, c, 0, 0, 0);
}
__device__ __forceinline__ int fidx(int row, int k) {
    return ((k >> 5) << 9) + ((((k >> 3) & 3) << 4) + row) * 8 + (k & 7);
}

// LDS: h ping-pong 2*8192 | x-frag staging 64KB
#define LDS8_X    16384
#define LDS8_SIZE 81920

extern "C" __global__ void __launch_bounds__(512, 2)
gru_v8(const float* __restrict__ x, const float* __restrict__ Wx,
       const float* __restrict__ Wh, const float* __restrict__ bias,
       const float* __restrict__ fcw, const float* __restrict__ fcb,
       unsigned short* __restrict__ ws, float* __restrict__ out)
{
    extern __shared__ char lds[];
    char* hl = lds;                         // 16KB h ping-pong
    char* xf = lds + LDS8_X;                // 64KB x A-frags (32 t)

    const int tid = threadIdx.x;
    const int w = tid >> 6, l = tid & 63;
    const int cl = l & 15, kg = l >> 4;
    const int b0 = blockIdx.x << 4;
    const int tiles[6] = {2*w, 2*w+1, 16+2*w, 17+2*w, 32+2*w, 33+2*w};

    // r,z Wh register-resident for the whole kernel (128 regs), log2e-scaled
    v8s whB[4][8];
#pragma unroll
    for (int tt = 0; tt < 4; ++tt) {
        const float* src = Wh + (size_t)(tiles[tt]*16 + cl)*256 + kg*8;
#pragma unroll
        for (int ks = 0; ks < 8; ++ks)
            whB[tt][ks] = wfrag(src + ks*32, LOG2E);
    }

    // h0 = 0 (buffer 0)
    for (int i = tid; i < 2048; i += 512) ((unsigned int*)hl)[i] = 0u;
    float hprev[8] = {0, 0, 0, 0, 0, 0, 0, 0};

    unsigned short* gxb = ws + (size_t)blockIdx.x * (CHUNK * 12288);

    // phase-A constants
    const int tl_x  = tid >> 4;
    const int k0    = (tid & 15) << 2;
    const int k2x   = k0 >> 5;
    const int laned = ((k0 & 31) >> 3) << 4;
    const int e2    = (k0 & 7) << 1;
    char* const xfd = xf + (tl_x*2 + k2x)*1024 + e2;

    for (int c = 0; c < NCHUNK; ++c) {
        const int c0 = c << 5;
        __syncthreads();                    // prev chunk fully consumed

        // ---------- A: stage chunk's x as MFMA A-frags in LDS ----------
#pragma unroll
        for (int r = 0; r < 16; ++r) {
            f32x4 v = *(const f32x4*)(x + ((size_t)(b0 + r) << 16)
                                        + (c0 << 6) + (tid << 2));
            unsigned int p0 = (unsigned int)f2b(v[0]) | ((unsigned int)f2b(v[1]) << 16);
            unsigned int p1 = (unsigned int)f2b(v[2]) | ((unsigned int)f2b(v[3]) << 16);
            u32x2 pk = {p0, p1};
            *(u32x2*)(xfd + (laned + r)*16) = pk;
        }
        __syncthreads();

        // ---------- B: prepass gx = x@Wx + b (prescaled, fp16) ----------
        {
            v8s wxr[12];
            float bv[6];
#pragma unroll
            for (int tt = 0; tt < 6; ++tt) {
                const float sc = (tt < 4) ? LOG2E : 2.0f*LOG2E;
                const float* s0 = Wx + (size_t)(tiles[tt]*16 + cl)*64 + kg*8;
                wxr[tt*2]   = wfrag(s0, sc);
                wxr[tt*2+1] = wfrag(s0 + 32, sc);
                bv[tt] = bias[tiles[tt]*16 + cl] * sc;
            }
            const v8s* xv = (const v8s*)xf;
            unsigned int* gp = (unsigned int*)(gxb + (size_t)((w << 6) + l) * 24);
            for (int tl = 0; tl < CHUNK; ++tl) {
                v8s a0 = xv[(tl*2)*64 + l];
                v8s a1 = xv[(tl*2+1)*64 + l];
                f32x4 acc[6];
#pragma unroll
                for (int tt = 0; tt < 6; ++tt)
                    acc[tt] = f32x4{bv[tt], bv[tt], bv[tt], bv[tt]};
#pragma unroll
                for (int tt = 0; tt < 6; ++tt) {
                    acc[tt] = MF(a0, wxr[tt*2],   acc[tt]);
                    acc[tt] = MF(a1, wxr[tt*2+1], acc[tt]);
                }
                unsigned int q[12];
#pragma unroll
                for (int tt = 0; tt < 6; ++tt) {
                    q[tt*2]   = (unsigned int)f2h(acc[tt][0]) | ((unsigned int)f2h(acc[tt][1]) << 16);
                    q[tt*2+1] = (unsigned int)f2h(acc[tt][2]) | ((unsigned int)f2h(acc[tt][3]) << 16);
                }
                u32x4 s0 = {q[0], q[1], q[2],  q[3]};
                u32x4 s1 = {q[4], q[5], q[6],  q[7]};
                u32x4 s2 = {q[8], q[9], q[10], q[11]};
                *(u32x4*)(gp)     = s0;
                *(u32x4*)(gp + 4) = s1;
                *(u32x4*)(gp + 8) = s2;
                gp += 12 * 512;             // next t record block
            }
        }
        __syncthreads();                    // vmcnt drained; same-thread RAW needs no fence

        // ---------- C: scan 32 steps, pure register Wh ----------
        {
            v8s whN[2][8];                  // n-gate tiles, 2*log2e
#pragma unroll
            for (int j = 0; j < 2; ++j) {
                const float* src = Wh + (size_t)(512 + (2*w + j)*16 + cl)*256 + kg*8;
#pragma unroll
                for (int ks = 0; ks < 8; ++ks)
                    whN[j][ks] = wfrag(src + ks*32, 2.0f*LOG2E);
            }
            const unsigned short* gq0 = gxb + (size_t)((w << 6) + l) * 24;
            for (int tl = 0; tl < CHUNK; ++tl) {
                const int t = c0 + tl;
                __syncthreads();
                const int cur = t & 1;
                const v8s* hb = (const v8s*)(hl + cur * 8192);

                // gx record: 3 coalesced dwordx4 (L2-hot, consumed post-MFMA)
                const u32x4* gq = (const u32x4*)(gq0 + (size_t)tl * 12288);
                u32x4 gr = gq[0], gz = gq[1], gn = gq[2];

                f32x4 aR[2] = {{0,0,0,0},{0,0,0,0}},
                      aZ[2] = {{0,0,0,0},{0,0,0,0}},
                      aN[2] = {{0,0,0,0},{0,0,0,0}};
#pragma unroll
                for (int ks = 0; ks < 8; ++ks) {
                    v8s a = hb[(ks << 6) + l];
                    aR[0] = MF(a, whB[0][ks], aR[0]);
                    aR[1] = MF(a, whB[1][ks], aR[1]);
                    aZ[0] = MF(a, whB[2][ks], aZ[0]);
                    aZ[1] = MF(a, whB[3][ks], aZ[1]);
                    aN[0] = MF(a, whN[0][ks], aN[0]);
                    aN[1] = MF(a, whN[1][ks], aN[1]);
                }

                unsigned short* hn = (unsigned short*)(hl + (cur ^ 1) * 8192);
#pragma unroll
                for (int p = 0; p < 2; ++p) {
                    const int ch = (w << 5) + (p << 4) + cl;
                    const int chbase = ((ch >> 5) << 9) + (((ch >> 3) & 3) << 7) + (ch & 7);
#pragma unroll
                    for (int i = 0; i < 4; ++i) {
                        const int dw = p*2 + (i >> 1), hi = i & 1;
                        float rg = sg(aR[p][i] + hxu(gr[dw], hi));
                        float zg = sg(aZ[p][i] + hxu(gz[dw], hi));
                        float nv = __builtin_fmaf(rg, aN[p][i], hxu(gn[dw], hi));
                        float ng = __builtin_fmaf(2.0f, sg(nv), -1.0f);
                        float hy = ng + zg * (hprev[p*4 + i] - ng);
                        hprev[p*4 + i] = hy;
                        hn[chbase + ((kg << 2) + i) * 8] = f2b(hy);
                    }
                }
            }
        }
    }

    __syncthreads();
    // logits from hT (buffer 0 after 1024 steps)
    const unsigned short* hf = (const unsigned short*)hl;
    if (tid < 160) {
        int row = tid / 10, cls = tid - row * 10;
        float s = fcb[cls];
        const float* wrow = fcw + cls * 256;
        for (int k = 0; k < 256; ++k)
            s += b2f(hf[fidx(row, k)]) * wrow[k];
        out[(b0 + row) * 10 + cls] = s;
    }
}

// ================= fallback (ws too small): R3 kernel, unscaled =================
#define FB_LDS_SIZE 151552
extern "C" __global__ void __launch_bounds__(512, 2)
gru_fb(const float* __restrict__ x, const float* __restrict__ Wx,
       const float* __restrict__ Wh, const float* __restrict__ bias,
       const float* __restrict__ fcw, const float* __restrict__ fcb,
       float* __restrict__ out)
{
    extern __shared__ char lds[];
    v8s* whn = (v8s*)lds;
    char* hl = lds + 131072;
    char* xl = lds + 147456;
    const int tid = threadIdx.x;
    const int w = tid >> 6, l = tid & 63;
    const int cl = l & 15, kg = l >> 4;
    const int b0 = blockIdx.x << 4;
    const int tiles[6] = {2*w, 2*w+1, 16+2*w, 17+2*w, 32+2*w, 33+2*w};

    for (int f = w; f < 128; f += 8) {
        int t5 = f >> 3, ks = f & 7;
        const float* src = Wh + (size_t)(512 + t5*16 + cl)*256 + ks*32 + kg*8;
        whn[f*64 + l] = wfrag(src, 1.0f);
    }
    v8s whB[4][8];
#pragma unroll
    for (int tt = 0; tt < 4; ++tt) {
        const float* src = Wh + (size_t)(tiles[tt]*16 + cl)*256 + kg*8;
#pragma unroll
        for (int ks = 0; ks < 8; ++ks)
            whB[tt][ks] = wfrag(src + ks*32, 1.0f);
    }
    float brv[2], bzv[2], bhv[2];
#pragma unroll
    for (int p = 0; p < 2; ++p) {
        int ch = (w << 5) + (p << 4) + cl;
        brv[p] = bias[ch]; bzv[p] = bias[256+ch]; bhv[p] = bias[512+ch];
    }
    for (int i = tid; i < 2048; i += 512) ((unsigned int*)hl)[i] = 0u;
    const int xr = tid >> 5, xc = (tid & 31) << 1;
    const int xidx = fidx(xr, xc);
    const float* xp = x + (((size_t)(b0 + xr)) << 16) + xc;
    {
        unsigned int pk = (unsigned int)f2b(xp[0]) | ((unsigned int)f2b(xp[1]) << 16);
        *(unsigned int*)(xl + xidx*2) = pk;
    }
    xp += 64;
    const int wn0 = (2*w)*8, wn1 = (2*w+1)*8;

    for (int t = 0; t < 1024; ++t) {
        __syncthreads();
        const int cur = t & 1;
        const v8s* hb = (const v8s*)(hl + cur*8192);
        const v8s* xb = (const v8s*)(xl + cur*2048);
        float xv0 = 0.0f, xv1 = 0.0f;
        if (t < 1023) { xv0 = xp[0]; xv1 = xp[1]; xp += 64; }
        v8s wxr[12];
#pragma unroll
        for (int tt = 0; tt < 6; ++tt) {
            const float* s0 = Wx + (size_t)(tiles[tt]*16 + cl)*64 + kg*8;
            wxr[tt*2]   = wfrag(s0, 1.0f);
            wxr[tt*2+1] = wfrag(s0 + 32, 1.0f);
        }
        f32x4 acc[8];
#pragma unroll
        for (int i = 0; i < 8; ++i) acc[i] = f32x4{0,0,0,0};
#pragma unroll
        for (int ks = 0; ks < 8; ++ks) {
            v8s a = hb[(ks << 6) + l];
            v8s n0 = whn[(wn0 + ks)*64 + l];
            v8s n1 = whn[(wn1 + ks)*64 + l];
            acc[0] = MF(a, whB[0][ks], acc[0]);
            acc[1] = MF(a, whB[1][ks], acc[1]);
            acc[2] = MF(a, whB[2][ks], acc[2]);
            acc[3] = MF(a, whB[3][ks], acc[3]);
            acc[4] = MF(a, n0, acc[4]);
            acc[5] = MF(a, n1, acc[5]);
        }
#pragma unroll
        for (int k2 = 0; k2 < 2; ++k2) {
            v8s ax = xb[(k2 << 6) + l];
            acc[0] = MF(ax, wxr[0+k2], acc[0]);
            acc[1] = MF(ax, wxr[2+k2], acc[1]);
            acc[2] = MF(ax, wxr[4+k2], acc[2]);
            acc[3] = MF(ax, wxr[6+k2], acc[3]);
            acc[6] = MF(ax, wxr[8+k2], acc[6]);
            acc[7] = MF(ax, wxr[10+k2], acc[7]);
        }
        const unsigned short* hc16 = (const unsigned short*)hb;
        unsigned short* hn16 = (unsigned short*)(hl + ((cur ^ 1) * 8192));
#pragma unroll
        for (int p = 0; p < 2; ++p) {
            int ch = (w << 5) + (p << 4) + cl;
            int chbase = ((ch >> 5) << 9) + (((ch >> 3) & 3) << 7) + (ch & 7);
#pragma unroll
            for (int i = 0; i < 4; ++i) {
                int row = (kg << 2) + i;
                int idx = chbase + (row << 3);
                float rg = sigm(acc[p][i] + brv[p]);
                float zg = sigm(acc[2+p][i] + bzv[p]);
                float ng = tanh_(acc[6+p][i] + bhv[p] + rg * acc[4+p][i]);
                float hold = b2f(hc16[idx]);
                float hy = ng + zg * (hold - ng);
                hn16[idx] = f2b(hy);
            }
        }
        if (t < 1023) {
            unsigned int pk = (unsigned int)f2b(xv0) | ((unsigned int)f2b(xv1) << 16);
            *(unsigned int*)(xl + ((cur ^ 1) * 2048) + xidx*2) = pk;
        }
    }
    __syncthreads();
    const unsigned short* hf = (const unsigned short*)hl;
    if (tid < 160) {
        int row = tid / 10, cls = tid - row * 10;
        float s = fcb[cls];
        const float* wrow = fcw + cls * 256;
        for (int k = 0; k < 256; ++k)
            s += b2f(hf[fidx(row, k)]) * wrow[k];
        out[(b0 + row)*10 + cls] = s;
    }
}

extern "C" void kernel_launch(void* const* d_in, const int* in_sizes, int n_in,
                              void* d_out, int out_size, void* d_ws, size_t ws_size,
                              hipStream_t stream) {
    const float* x    = (const float*)d_in[0];
    const float* Wx   = (const float*)d_in[1];
    const float* Wh   = (const float*)d_in[2];
    const float* bias = (const float*)d_in[3];
    const float* fcw  = (const float*)d_in[4];
    const float* fcb  = (const float*)d_in[5];

    if (ws_size >= WS_NEED) {
        (void)hipFuncSetAttribute((const void*)gru_v8,
                                  hipFuncAttributeMaxDynamicSharedMemorySize, LDS8_SIZE);
        gru_v8<<<dim3(32), dim3(512), LDS8_SIZE, stream>>>(
            x, Wx, Wh, bias, fcw, fcb, (unsigned short*)d_ws, (float*)d_out);
    } else {
        (void)hipFuncSetAttribute((const void*)gru_fb,
                                  hipFuncAttributeMaxDynamicSharedMemorySize, FB_LDS_SIZE);
        gru_fb<<<dim3(32), dim3(512), FB_LDS_SIZE, stream>>>(
            x, Wx, Wh, bias, fcw, fcb, (float*)d_out);
    }
}

// Round 5
// 1994.984 us; speedup vs baseline: 1.4463x; 1.4463x over previous
//
#include <hip/hip_runtime.h>

// R10: 1024-thread / 16-wave blocks — occupancy attack.
// R7/R9 post-mortem: all three pipes (VALU 43%, MFMA-lat 45%, LDS ~39%) sat
// under-utilized at 2 waves/SIMD; off-chip gx staging (R9) regressed via
// latency. Weights need ~1920 VGPRs/CU, so 512-thread blocks are stuck.
// R10: 16 waves, each owning ONE (r,z,n) 16-channel tile-group with unified
// A=[h;x] (K=320, 10 ks). r,z (10 frags) + n-x-part (2) register-resident
// (~88 regs); n-gate Wh (8 frags/wave, wave-disjoint) in LDS. ~124 regs/wave
// -> 4 waves/SIMD. Per step/wave: 30 MFMA, 18KB LDS read, 12 sg/lane.
// Single barrier per step, no workspace, no global round trips.

typedef short v8s __attribute__((ext_vector_type(8)));   // 8 bf16
typedef float f32x4 __attribute__((ext_vector_type(4)));

#define LOG2E 1.4426950408889634f

__device__ __forceinline__ unsigned short f2b(float f) {
    unsigned int u = __float_as_uint(f);
    u += 0x7FFFu + ((u >> 16) & 1u);       // RNE
    return (unsigned short)(u >> 16);
}
__device__ __forceinline__ float b2f(unsigned short h) {
    return __uint_as_float(((unsigned int)h) << 16);
}
__device__ __forceinline__ v8s cvt8(f32x4 a, f32x4 b) {
    v8s r;
#pragma unroll
    for (int j = 0; j < 4; ++j) { r[j] = (short)f2b(a[j]); r[4 + j] = (short)f2b(b[j]); }
    return r;
}
__device__ __forceinline__ v8s wfrag(const float* src, float s) {
    f32x4 a = *(const f32x4*)src, b = *(const f32x4*)(src + 4);
    a *= s; b *= s;
    return cvt8(a, b);
}
__device__ __forceinline__ float rcpf(float v) {
#if __has_builtin(__builtin_amdgcn_rcpf)
    return __builtin_amdgcn_rcpf(v);
#else
    return 1.0f / v;
#endif
}
__device__ __forceinline__ float exp2f_(float v) {
#if __has_builtin(__builtin_amdgcn_exp2f)
    return __builtin_amdgcn_exp2f(v);
#else
    return __exp2f(v);
#endif
}
// sigmoid of log2e-prescaled preactivation (HW-validated R6/R7)
__device__ __forceinline__ float sg(float v) { return rcpf(1.0f + exp2f_(-v)); }
__device__ __forceinline__ f32x4 MF(v8s a, v8s b, f32x4 c) {
    return __builtin_amdgcn_mfma_f32_16x16x32_bf16(a, b, c, 0, 0, 0);
}
// A-frag order index for element (row, k): u16 units
__device__ __forceinline__ int fidx(int row, int k) {
    return ((k >> 5) << 9) + ((((k >> 3) & 3) << 4) + row) * 8 + (k & 7);
}

// LDS: n-gate Wh frags 131072 | h ping-pong 2*8192 | x ping-pong 2*2048
#define LDSX_WN   0
#define LDSX_H    131072
#define LDSX_X    147456
#define LDSX_SIZE 151552

extern "C" __global__ void __launch_bounds__(1024, 4)
gru_v10(const float* __restrict__ x, const float* __restrict__ Wx,
        const float* __restrict__ Wh, const float* __restrict__ bias,
        const float* __restrict__ fcw, const float* __restrict__ fcb,
        float* __restrict__ out)
{
    extern __shared__ char lds[];
    v8s* wnl = (v8s*)(lds + LDSX_WN);      // 16 waves * 8 ks frags
    char* hl = lds + LDSX_H;
    char* xl = lds + LDSX_X;

    const int tid = threadIdx.x;
    const int w = tid >> 6, l = tid & 63;  // w in [0,16)
    const int cl = l & 15, kg = l >> 4;
    const int b0 = blockIdx.x << 4;
    const int ch = (w << 4) + cl;          // this lane's h-channel [0,256)

    // n-gate Wh (rows 512+ch): 8 frags -> LDS (wave-disjoint), scale 2log2e
#pragma unroll
    for (int ks = 0; ks < 8; ++ks)
        wnl[(w*8 + ks)*64 + l] =
            wfrag(Wh + (size_t)(512 + ch)*256 + ks*32 + kg*8, 2.0f*LOG2E);

    // r,z: 10 unified-k frags each (ks 0..7 from Wh, 8..9 from Wx), log2e;
    // n-gate x-part (2 frags), 2log2e.  88 VGPRs total.
    v8s rW[10], zW[10], nX[2];
#pragma unroll
    for (int ks = 0; ks < 8; ++ks) {
        rW[ks] = wfrag(Wh + (size_t)ch*256 + ks*32 + kg*8, LOG2E);
        zW[ks] = wfrag(Wh + (size_t)(256 + ch)*256 + ks*32 + kg*8, LOG2E);
    }
#pragma unroll
    for (int k2 = 0; k2 < 2; ++k2) {
        rW[8+k2] = wfrag(Wx + (size_t)ch*64 + k2*32 + kg*8, LOG2E);
        zW[8+k2] = wfrag(Wx + (size_t)(256 + ch)*64 + k2*32 + kg*8, LOG2E);
        nX[k2]   = wfrag(Wx + (size_t)(512 + ch)*64 + k2*32 + kg*8, 2.0f*LOG2E);
    }
    const float br = bias[ch] * LOG2E;
    const float bz = bias[256 + ch] * LOG2E;
    const float bn = bias[512 + ch] * (2.0f*LOG2E);

    // epilogue h-write base for this lane's channel
    const int chb = ((ch >> 5) << 9) + (((ch >> 3) & 3) << 7) + (ch & 7);

    // h0 = 0 (buffer 0)
    for (int i = tid; i < 2048; i += 1024) ((unsigned int*)hl)[i] = 0u;
    float hprev[4] = {0, 0, 0, 0};

    // x staging: row/col for this thread; stage t=0 into buffer 0
    const int xr = tid >> 6, xc = tid & 63;
    const int xidx = fidx(xr, xc);
    {
        float v = x[((size_t)(b0 + xr) * 1024 + 0) * 64 + xc];
        *(unsigned short*)(xl + xidx*2) = f2b(v);
    }

    for (int t = 0; t < 1024; ++t) {
        __syncthreads();
        const int cur = t & 1;
        const v8s* hb = (const v8s*)(hl + cur * 8192);
        const v8s* xb = (const v8s*)(xl + cur * 2048);

        // prefetch next timestep's x (1 f32/thread, coalesced; consumed at end)
        float xv = 0.0f;
        if (t < 1023)
            xv = x[((size_t)(b0 + xr) * 1024 + (t + 1)) * 64 + xc];

        f32x4 aR = {br, br, br, br};
        f32x4 aZ = {bz, bz, bz, bz};
        f32x4 aNh = {0, 0, 0, 0};
        f32x4 aNx = {bn, bn, bn, bn};

#pragma unroll
        for (int ks = 0; ks < 8; ++ks) {
            v8s a  = hb[(ks << 6) + l];
            v8s nW = wnl[(w*8 + ks)*64 + l];
            aR  = MF(a, rW[ks], aR);
            aZ  = MF(a, zW[ks], aZ);
            aNh = MF(a, nW, aNh);
        }
#pragma unroll
        for (int k2 = 0; k2 < 2; ++k2) {
            v8s ax = xb[(k2 << 6) + l];
            aR  = MF(ax, rW[8+k2], aR);
            aZ  = MF(ax, zW[8+k2], aZ);
            aNx = MF(ax, nX[k2], aNx);
        }

        unsigned short* hn = (unsigned short*)(hl + (cur ^ 1) * 8192);
#pragma unroll
        for (int i = 0; i < 4; ++i) {
            float rg = sg(aR[i]);
            float zg = sg(aZ[i]);
            float nv = __builtin_fmaf(rg, aNh[i], aNx[i]);
            float ng = __builtin_fmaf(2.0f, sg(nv), -1.0f);
            float hy = ng + zg * (hprev[i] - ng);
            hprev[i] = hy;
            hn[chb + ((kg << 2) + i) * 8] = f2b(hy);
        }
        if (t < 1023)
            *(unsigned short*)(xl + (cur ^ 1) * 2048 + xidx*2) = f2b(xv);
    }

    __syncthreads();
    // logits from hT (buffer 0 after 1024 steps)
    const unsigned short* hf = (const unsigned short*)hl;
    if (tid < 160) {
        int row = tid / 10, cls = tid - row * 10;
        float s = fcb[cls];
        const float* wrow = fcw + cls * 256;
        for (int k = 0; k < 256; ++k)
            s += b2f(hf[fidx(row, k)]) * wrow[k];
        out[(b0 + row) * 10 + cls] = s;
    }
}

extern "C" void kernel_launch(void* const* d_in, const int* in_sizes, int n_in,
                              void* d_out, int out_size, void* d_ws, size_t ws_size,
                              hipStream_t stream) {
    const float* x    = (const float*)d_in[0];
    const float* Wx   = (const float*)d_in[1];
    const float* Wh   = (const float*)d_in[2];
    const float* bias = (const float*)d_in[3];
    const float* fcw  = (const float*)d_in[4];
    const float* fcb  = (const float*)d_in[5];
    (void)d_ws; (void)ws_size;

    (void)hipFuncSetAttribute((const void*)gru_v10,
                              hipFuncAttributeMaxDynamicSharedMemorySize, LDSX_SIZE);
    gru_v10<<<dim3(32), dim3(1024), LDSX_SIZE, stream>>>(
        x, Wx, Wh, bias, fcw, fcb, (float*)d_out);
}